// Round 1
// baseline (158.932 us; speedup 1.0000x reference)
//
#include <hip/hip_runtime.h>

typedef __attribute__((ext_vector_type(8))) short short8;   // 8 bf16 (4 VGPRs)
typedef __attribute__((ext_vector_type(4))) float f32x4;    // 4 fp32 acc

#define CTX 32
#define ND  64
#define NH  64

// ---- LDS layout (bytes) ----
// W tiles stored TRANSPOSED: Wt[h][d], row stride padded 64->72 bf16 = 144 B
#define WSTRIDE 144
#define W_TILE  (64 * WSTRIDE)          // 9216
#define OFF_WQH 0
#define OFF_WQL (OFF_WQH + W_TILE)
#define OFF_WKH (OFF_WQL + W_TILE)
#define OFF_WKL (OFF_WKH + W_TILE)
#define OFF_WVH (OFF_WKL + W_TILE)
#define OFF_WAVE (OFF_WVH + W_TILE)     // 46080

// per-wave region: q/k tiles [32][72] bf16 (stride 144 B)
#define QKTILE (32 * WSTRIDE)           // 4608
#define PW_QH 0
#define PW_QL (QKTILE)
#define PW_KH (2 * QKTILE)
#define PW_KL (3 * QKTILE)
#define PW_VT (PW_QH)                   // vT[64][40] (5120 B) aliases qH/qL (dead after QK)
#define PSTR 80                         // p / vT row stride: 32->40 bf16 = 80 B
#define PW_P  (4 * QKTILE)              // p[32][40] = 2560 B
#define WAVE_BYTES (4 * QKTILE + CTX * PSTR)   // 20992
#define LDS_BYTES (OFF_WAVE + 4 * WAVE_BYTES)  // 130048 (= 127 KB)

__device__ __forceinline__ unsigned short f2bf(float f) {
  unsigned int u = __builtin_bit_cast(unsigned int, f);
  u += 0x7FFFu + ((u >> 16) & 1u);     // RNE
  return (unsigned short)(u >> 16);
}
__device__ __forceinline__ float bf2f(unsigned short b) {
  unsigned int u = ((unsigned int)b) << 16;
  return __builtin_bit_cast(float, u);
}

#define MFMA(a, b, c) __builtin_amdgcn_mfma_f32_16x16x32_bf16((a), (b), (c), 0, 0, 0)

__global__ __launch_bounds__(256) void head_fused(
    const float* __restrict__ x, const float* __restrict__ Wk,
    const float* __restrict__ Wq, const float* __restrict__ Wv,
    float* __restrict__ out)
{
  __shared__ __align__(16) char lds[LDS_BYTES];
  const int tid = threadIdx.x;

  // ---- stage weights: fp32 -> bf16 hi/lo, transposed [h][d] ----
  for (int idx = tid; idx < ND * NH; idx += 256) {
    const int d = idx >> 6, h = idx & 63;
    const int woff = h * WSTRIDE + d * 2;
    const float fq = Wq[idx];
    const unsigned short qh = f2bf(fq);
    *(unsigned short*)(lds + OFF_WQH + woff) = qh;
    *(unsigned short*)(lds + OFF_WQL + woff) = f2bf(fq - bf2f(qh));
    const float fk = Wk[idx];
    const unsigned short kh = f2bf(fk);
    *(unsigned short*)(lds + OFF_WKH + woff) = kh;
    *(unsigned short*)(lds + OFF_WKL + woff) = f2bf(fk - bf2f(kh));
    *(unsigned short*)(lds + OFF_WVH + woff) = f2bf(Wv[idx]);
  }
  __syncthreads();

  const int wid  = tid >> 6;
  const int lane = tid & 63;
  const int c = lane & 15;   // within-tile col / row-group col
  const int g = lane >> 4;   // k-chunk group
  char* const wl = lds + OFF_WAVE + wid * WAVE_BYTES;

  const long b = (long)blockIdx.x * 4 + wid;
  const float* const xb = x + b * (CTX * ND);

  // ---- x -> A-fragments in registers (hi/lo). A[l&15][8*(l>>4)+j] ----
  short8 xh[2][2], xl[2][2];
  #pragma unroll
  for (int mt = 0; mt < 2; ++mt) {
    #pragma unroll
    for (int kt = 0; kt < 2; ++kt) {
      const float* p = xb + (16 * mt + c) * ND + 32 * kt + 8 * g;
      const f32x4 a0 = *(const f32x4*)(p);
      const f32x4 a1 = *(const f32x4*)(p + 4);
      short8 hi, lo;
      #pragma unroll
      for (int j = 0; j < 4; ++j) {
        const unsigned short h0 = f2bf(a0[j]);
        hi[j] = (short)h0;
        lo[j] = (short)f2bf(a0[j] - bf2f(h0));
        const unsigned short h1 = f2bf(a1[j]);
        hi[4 + j] = (short)h1;
        lo[4 + j] = (short)f2bf(a1[j] - bf2f(h1));
      }
      xh[mt][kt] = hi;
      xl[mt][kt] = lo;
    }
  }

  // ---- q,k projections: 3-term split (xh*Wh + xh*Wl + xl*Wh) -> LDS hi/lo ----
  #pragma unroll
  for (int which = 0; which < 2; ++which) {
    const int baseH = which ? OFF_WKH : OFF_WQH;
    const int baseL = which ? OFF_WKL : OFF_WQL;
    char* const outH = wl + (which ? PW_KH : PW_QH);
    char* const outL = wl + (which ? PW_KL : PW_QL);
    #pragma unroll
    for (int nt = 0; nt < 4; ++nt) {
      f32x4 acc0 = {0.f, 0.f, 0.f, 0.f};
      f32x4 acc1 = {0.f, 0.f, 0.f, 0.f};
      #pragma unroll
      for (int kt = 0; kt < 2; ++kt) {
        const int woff = (16 * nt + c) * WSTRIDE + 64 * kt + 16 * g;
        const short8 bh = *(const short8*)(lds + baseH + woff);
        const short8 bl = *(const short8*)(lds + baseL + woff);
        acc0 = MFMA(xh[0][kt], bh, acc0);
        acc0 = MFMA(xh[0][kt], bl, acc0);
        acc0 = MFMA(xl[0][kt], bh, acc0);
        acc1 = MFMA(xh[1][kt], bh, acc1);
        acc1 = MFMA(xh[1][kt], bl, acc1);
        acc1 = MFMA(xl[1][kt], bh, acc1);
      }
      // D-frag: row = 4*(l>>4)+j (+16*mt), col = l&15 (+16*nt). Store [t][h] hi/lo.
      #pragma unroll
      for (int j = 0; j < 4; ++j) {
        const int col = (16 * nt + c) * 2;
        {
          const float v = acc0[j];
          const unsigned short h = f2bf(v);
          const int off = (4 * g + j) * WSTRIDE + col;
          *(unsigned short*)(outH + off) = h;
          *(unsigned short*)(outL + off) = f2bf(v - bf2f(h));
        }
        {
          const float v = acc1[j];
          const unsigned short h = f2bf(v);
          const int off = (16 + 4 * g + j) * WSTRIDE + col;
          *(unsigned short*)(outH + off) = h;
          *(unsigned short*)(outL + off) = f2bf(v - bf2f(h));
        }
      }
    }
  }

  // ---- QK^T: P = Q·K^T (contract h), 3-term split ----
  f32x4 pa[2][2] = {{{0.f,0.f,0.f,0.f},{0.f,0.f,0.f,0.f}},
                    {{0.f,0.f,0.f,0.f},{0.f,0.f,0.f,0.f}}};
  #pragma unroll
  for (int kt = 0; kt < 2; ++kt) {
    short8 aH[2], aL[2], bH[2], bL[2];
    #pragma unroll
    for (int i = 0; i < 2; ++i) {
      const int off = (16 * i + c) * WSTRIDE + 64 * kt + 16 * g;
      aH[i] = *(const short8*)(wl + PW_QH + off);
      aL[i] = *(const short8*)(wl + PW_QL + off);
      bH[i] = *(const short8*)(wl + PW_KH + off);
      bL[i] = *(const short8*)(wl + PW_KL + off);
    }
    #pragma unroll
    for (int mt = 0; mt < 2; ++mt) {
      #pragma unroll
      for (int nt = 0; nt < 2; ++nt) {
        pa[mt][nt] = MFMA(aH[mt], bH[nt], pa[mt][nt]);
        pa[mt][nt] = MFMA(aH[mt], bL[nt], pa[mt][nt]);
        pa[mt][nt] = MFMA(aL[mt], bH[nt], pa[mt][nt]);
      }
    }
  }

  // ---- causal mask + softmax (fp32), store P as bf16 [t][s] stride 80 B ----
  char* const pbuf = wl + PW_P;
  #pragma unroll
  for (int mt = 0; mt < 2; ++mt) {
    #pragma unroll
    for (int j = 0; j < 4; ++j) {
      const int t = 16 * mt + 4 * g + j;
      float v0 = pa[mt][0][j] * 8.0f;       // s = c
      float v1 = pa[mt][1][j] * 8.0f;       // s = 16 + c
      if (c > t)      v0 = -__builtin_inff();
      if (16 + c > t) v1 = -__builtin_inff();
      float m = fmaxf(v0, v1);
      m = fmaxf(m, __shfl_xor(m, 1));
      m = fmaxf(m, __shfl_xor(m, 2));
      m = fmaxf(m, __shfl_xor(m, 4));
      m = fmaxf(m, __shfl_xor(m, 8));
      const float e0 = __expf(v0 - m);
      const float e1 = __expf(v1 - m);
      float s = e0 + e1;
      s += __shfl_xor(s, 1);
      s += __shfl_xor(s, 2);
      s += __shfl_xor(s, 4);
      s += __shfl_xor(s, 8);
      const float r = 1.0f / s;
      *(unsigned short*)(pbuf + t * PSTR + c * 2)        = f2bf(e0 * r);
      *(unsigned short*)(pbuf + t * PSTR + (16 + c) * 2) = f2bf(e1 * r);
    }
  }

  // ---- v projection (single term), stored TRANSPOSED vT[h][s] (aliases q tiles) ----
  #pragma unroll
  for (int nt = 0; nt < 4; ++nt) {
    f32x4 acc0 = {0.f, 0.f, 0.f, 0.f};
    f32x4 acc1 = {0.f, 0.f, 0.f, 0.f};
    #pragma unroll
    for (int kt = 0; kt < 2; ++kt) {
      const int woff = (16 * nt + c) * WSTRIDE + 64 * kt + 16 * g;
      const short8 bv = *(const short8*)(lds + OFF_WVH + woff);
      acc0 = MFMA(xh[0][kt], bv, acc0);
      acc1 = MFMA(xh[1][kt], bv, acc1);
    }
    #pragma unroll
    for (int j = 0; j < 4; ++j) {
      char* const vrow = wl + PW_VT + (16 * nt + c) * PSTR;
      *(unsigned short*)(vrow + (4 * g + j) * 2)      = f2bf(acc0[j]);
      *(unsigned short*)(vrow + (16 + 4 * g + j) * 2) = f2bf(acc1[j]);
    }
  }

  // ---- PV: out = P·V (K = 32, single MFMA per tile) ----
  const short8 ap0 = *(const short8*)(pbuf + c * PSTR + 16 * g);
  const short8 ap1 = *(const short8*)(pbuf + (16 + c) * PSTR + 16 * g);
  float* const ob = out + b * (CTX * NH);
  #pragma unroll
  for (int nt = 0; nt < 4; ++nt) {
    const short8 bv = *(const short8*)(wl + PW_VT + (16 * nt + c) * PSTR + 16 * g);
    f32x4 o0 = {0.f, 0.f, 0.f, 0.f};
    f32x4 o1 = {0.f, 0.f, 0.f, 0.f};
    o0 = MFMA(ap0, bv, o0);
    o1 = MFMA(ap1, bv, o1);
    #pragma unroll
    for (int j = 0; j < 4; ++j) {
      ob[(4 * g + j) * NH + 16 * nt + c]        = o0[j];
      ob[(16 + 4 * g + j) * NH + 16 * nt + c]   = o1[j];
    }
  }
}

extern "C" void kernel_launch(void* const* d_in, const int* in_sizes, int n_in,
                              void* d_out, int out_size, void* d_ws, size_t ws_size,
                              hipStream_t stream) {
  // setup_inputs order: x, Wk, Wq, Wv  (all fp32)
  const float* x  = (const float*)d_in[0];
  const float* Wk = (const float*)d_in[1];
  const float* Wq = (const float*)d_in[2];
  const float* Wv = (const float*)d_in[3];
  float* out = (float*)d_out;
  const int batch = in_sizes[0] / (CTX * ND);   // 16384
  head_fused<<<dim3(batch / 4), dim3(256), 0, stream>>>(x, Wk, Wq, Wv, out);
}

// Round 2
// 65.861 us; speedup vs baseline: 2.4132x; 2.4132x over previous
//
#include <hip/hip_runtime.h>

typedef __attribute__((ext_vector_type(8))) short short8;   // 8 bf16 (4 VGPRs)
typedef __attribute__((ext_vector_type(4))) float f32x4;    // 4 fp32 acc

#define CTX 32
#define ND  64
#define NH  64
#define LOG2E_8 11.541560327111707f   // 8 * log2(e), folded into M

// ---- LDS layout (bytes) ----
// Shared weight tiles, 128 B rows, XOR-swizzled (16B block ^ (row&7))
#define OFF_MH 0                 // MtH [64][64] bf16  (Mt[d'][d] = 8*log2e*sum_h Wq[d][h]Wk[d'][h])
#define OFF_ML 8192              // MtL
#define OFF_WV 16384             // WvT [64][64] bf16  (WvT[h][d] = Wv[d][h])
#define OFF_WAVE 24576
// per-wave region:
//   rtH [32][40] @0 (2560), rtL @2560 (2560)   -- tmp half-tile round-trip, stride 80 B
//   vT  [64][40] @0 (5120)                     -- aliases rtH+rtL (dead after P)
//   P   [32][32] @5120 (2048)                  -- unpadded, stride 64 B
#define PWSTR 80
#define PW_RTH 0
#define PW_RTL 2560
#define PW_VT  0
#define PW_P   5120
#define WAVE_BYTES 7168
#define LDS_BYTES (OFF_WAVE + 4 * WAVE_BYTES)   // 53248 -> 3 WG/CU

__device__ __forceinline__ unsigned short f2bf(float f) {
  unsigned int u = __builtin_bit_cast(unsigned int, f);
  u += 0x7FFFu + ((u >> 16) & 1u);     // RNE
  return (unsigned short)(u >> 16);
}
__device__ __forceinline__ float bf2f(unsigned short b) {
  unsigned int u = ((unsigned int)b) << 16;
  return __builtin_bit_cast(float, u);
}

#define MFMA(a, b, c) __builtin_amdgcn_mfma_f32_16x16x32_bf16((a), (b), (c), 0, 0, 0)

// ---- precompute Mt = (Wq Wk^T)^T * 8*log2(e), bf16 hi/lo, into ws ----
__global__ __launch_bounds__(256) void mk_m(
    const float* __restrict__ Wq, const float* __restrict__ Wk,
    unsigned short* __restrict__ MtH, unsigned short* __restrict__ MtL)
{
  const int idx = blockIdx.x * 256 + threadIdx.x;   // [0,4096): idx = dp*64 + d
  const int dp = idx >> 6, d = idx & 63;
  const float* wq = Wq + d * 64;
  const float* wk = Wk + dp * 64;
  float acc = 0.f;
  #pragma unroll
  for (int h = 0; h < 64; ++h) acc = fmaf(wq[h], wk[h], acc);
  acc *= LOG2E_8;
  const unsigned short hi = f2bf(acc);
  MtH[idx] = hi;
  MtL[idx] = f2bf(acc - bf2f(hi));
}

__global__ __launch_bounds__(256, 3) void head_fused(
    const float* __restrict__ x, const float* __restrict__ Wv,
    const unsigned short* __restrict__ MtH_g, const unsigned short* __restrict__ MtL_g,
    float* __restrict__ out)
{
  __shared__ __align__(16) char lds[LDS_BYTES];
  const int tid = threadIdx.x;

  // ---- stage Mt hi/lo (u32 copies) + WvT (fp32->bf16, transposed), swizzled ----
  {
    const unsigned int* srcH = (const unsigned int*)MtH_g;
    const unsigned int* srcL = (const unsigned int*)MtL_g;
    #pragma unroll
    for (int i = 0; i < 8; ++i) {
      const int e = tid + 256 * i;            // u32 index [0,2048)
      const int row = e >> 5;
      const int byte = row * 128 + (((e & 31) * 4) ^ ((row & 7) << 4));
      *(unsigned int*)(lds + OFF_MH + byte) = srcH[e];
      *(unsigned int*)(lds + OFF_ML + byte) = srcL[e];
    }
    #pragma unroll
    for (int i = 0; i < 16; ++i) {
      const int e = tid + 256 * i;            // [0,4096): e = d*64 + h
      const int d = e >> 6, h = e & 63;
      const int byte = h * 128 + ((2 * d) ^ ((h & 7) << 4));
      *(unsigned short*)(lds + OFF_WV + byte) = f2bf(Wv[e]);
    }
  }
  __syncthreads();

  const int wid  = tid >> 6;
  const int lane = tid & 63;
  const int c = lane & 15;
  const int g = lane >> 4;
  char* const wl = lds + OFF_WAVE + wid * WAVE_BYTES;

  const long b = (long)blockIdx.x * 4 + wid;
  const float* const xb = x + b * (CTX * ND);

  // ---- x -> A-fragments hi/lo. A[lane&15][8*(lane>>4)+j] ----
  short8 xh[2][2], xl[2][2];
  #pragma unroll
  for (int mt = 0; mt < 2; ++mt) {
    #pragma unroll
    for (int kt = 0; kt < 2; ++kt) {
      const float* p = xb + (16 * mt + c) * ND + 32 * kt + 8 * g;
      const f32x4 a0 = *(const f32x4*)(p);
      const f32x4 a1 = *(const f32x4*)(p + 4);
      short8 hi, lo;
      #pragma unroll
      for (int j = 0; j < 4; ++j) {
        const unsigned short h0 = f2bf(a0[j]);
        hi[j] = (short)h0;
        lo[j] = (short)f2bf(a0[j] - bf2f(h0));
        const unsigned short h1 = f2bf(a1[j]);
        hi[4 + j] = (short)h1;
        lo[4 + j] = (short)f2bf(a1[j] - bf2f(h1));
      }
      xh[mt][kt] = hi;
      xl[mt][kt] = lo;
    }
  }

  // ---- tmp = X·Mt (3-term), interleaved per 32-col half with P += tmp·X^T ----
  f32x4 pa[2][2] = {{{0.f,0.f,0.f,0.f},{0.f,0.f,0.f,0.f}},
                    {{0.f,0.f,0.f,0.f},{0.f,0.f,0.f,0.f}}};
  #pragma unroll
  for (int kt = 0; kt < 2; ++kt) {
    #pragma unroll
    for (int ntl = 0; ntl < 2; ++ntl) {
      const int nt = 2 * kt + ntl;
      f32x4 a0 = {0.f, 0.f, 0.f, 0.f};
      f32x4 a1 = {0.f, 0.f, 0.f, 0.f};
      #pragma unroll
      for (int kk = 0; kk < 2; ++kk) {
        const int row = 16 * nt + c;
        const int byte = row * 128 + ((64 * kk + 16 * g) ^ ((row & 7) << 4));
        const short8 bh = *(const short8*)(lds + OFF_MH + byte);
        const short8 bl = *(const short8*)(lds + OFF_ML + byte);
        a0 = MFMA(xh[0][kk], bh, a0);
        a0 = MFMA(xh[0][kk], bl, a0);
        a0 = MFMA(xl[0][kk], bh, a0);
        a1 = MFMA(xh[1][kk], bh, a1);
        a1 = MFMA(xh[1][kk], bl, a1);
        a1 = MFMA(xl[1][kk], bh, a1);
      }
      // D-frag: row = 4g+j (+16), col = c (+16*ntl within rt). Store hi/lo.
      #pragma unroll
      for (int j = 0; j < 4; ++j) {
        const int col2 = 2 * (16 * ntl + c);
        const int off0 = (4 * g + j) * PWSTR + col2;
        const int off1 = (16 + 4 * g + j) * PWSTR + col2;
        const unsigned short h0 = f2bf(a0[j]);
        *(unsigned short*)(wl + PW_RTH + off0) = h0;
        *(unsigned short*)(wl + PW_RTL + off0) = f2bf(a0[j] - bf2f(h0));
        const unsigned short h1 = f2bf(a1[j]);
        *(unsigned short*)(wl + PW_RTH + off1) = h1;
        *(unsigned short*)(wl + PW_RTL + off1) = f2bf(a1[j] - bf2f(h1));
      }
    }
    // read tmp back as A-frags (same wave wrote -> in-order DS, no barrier)
    short8 tH[2], tL[2];
    #pragma unroll
    for (int i = 0; i < 2; ++i) {
      const int off = (16 * i + c) * PWSTR + 16 * g;
      tH[i] = *(const short8*)(wl + PW_RTH + off);
      tL[i] = *(const short8*)(wl + PW_RTL + off);
    }
    // B-operand for tmp·X^T over k=d in [32kt,32kt+32) is x's A-frag at kt
    #pragma unroll
    for (int mt = 0; mt < 2; ++mt) {
      #pragma unroll
      for (int nt2 = 0; nt2 < 2; ++nt2) {
        pa[mt][nt2] = MFMA(tH[mt], xh[nt2][kt], pa[mt][nt2]);
        pa[mt][nt2] = MFMA(tH[mt], xl[nt2][kt], pa[mt][nt2]);
        pa[mt][nt2] = MFMA(tL[mt], xh[nt2][kt], pa[mt][nt2]);
      }
    }
  }

  // ---- causal mask + softmax (log2-domain; scale pre-folded into M) ----
  char* const pbuf = wl + PW_P;
  #pragma unroll
  for (int mt = 0; mt < 2; ++mt) {
    #pragma unroll
    for (int j = 0; j < 4; ++j) {
      const int t = 16 * mt + 4 * g + j;
      float v0 = pa[mt][0][j];              // s = c
      float v1 = pa[mt][1][j];              // s = 16 + c
      if (c > t)      v0 = -__builtin_inff();
      if (16 + c > t) v1 = -__builtin_inff();
      float m = fmaxf(v0, v1);
      m = fmaxf(m, __shfl_xor(m, 1));
      m = fmaxf(m, __shfl_xor(m, 2));
      m = fmaxf(m, __shfl_xor(m, 4));
      m = fmaxf(m, __shfl_xor(m, 8));
      const float e0 = exp2f(v0 - m);
      const float e1 = exp2f(v1 - m);
      float s = e0 + e1;
      s += __shfl_xor(s, 1);
      s += __shfl_xor(s, 2);
      s += __shfl_xor(s, 4);
      s += __shfl_xor(s, 8);
      const float r = 1.0f / s;
      *(unsigned short*)(pbuf + t * 64 + 2 * c)        = f2bf(e0 * r);
      *(unsigned short*)(pbuf + t * 64 + 32 + 2 * c)   = f2bf(e1 * r);
    }
  }

  // ---- v = X·Wv (single term), stored transposed vT[h][s] (aliases rt) ----
  #pragma unroll
  for (int nt = 0; nt < 4; ++nt) {
    f32x4 a0 = {0.f, 0.f, 0.f, 0.f};
    f32x4 a1 = {0.f, 0.f, 0.f, 0.f};
    #pragma unroll
    for (int kk = 0; kk < 2; ++kk) {
      const int row = 16 * nt + c;
      const int byte = row * 128 + ((64 * kk + 16 * g) ^ ((row & 7) << 4));
      const short8 bv = *(const short8*)(lds + OFF_WV + byte);
      a0 = MFMA(xh[0][kk], bv, a0);
      a1 = MFMA(xh[1][kk], bv, a1);
    }
    #pragma unroll
    for (int j = 0; j < 4; ++j) {
      char* const vrow = wl + PW_VT + (16 * nt + c) * PWSTR;
      *(unsigned short*)(vrow + 2 * (4 * g + j))      = f2bf(a0[j]);
      *(unsigned short*)(vrow + 2 * (16 + 4 * g + j)) = f2bf(a1[j]);
    }
  }

  // ---- PV: out = P·V (K = 32, one MFMA per tile) ----
  const short8 ap0 = *(const short8*)(pbuf + c * 64 + 16 * g);
  const short8 ap1 = *(const short8*)(pbuf + (16 + c) * 64 + 16 * g);
  float* const ob = out + b * (CTX * NH);
  #pragma unroll
  for (int nt = 0; nt < 4; ++nt) {
    const short8 bv = *(const short8*)(wl + PW_VT + (16 * nt + c) * PWSTR + 16 * g);
    f32x4 o0 = {0.f, 0.f, 0.f, 0.f};
    f32x4 o1 = {0.f, 0.f, 0.f, 0.f};
    o0 = MFMA(ap0, bv, o0);
    o1 = MFMA(ap1, bv, o1);
    #pragma unroll
    for (int j = 0; j < 4; ++j) {
      ob[(4 * g + j) * NH + 16 * nt + c]      = o0[j];
      ob[(16 + 4 * g + j) * NH + 16 * nt + c] = o1[j];
    }
  }
}

extern "C" void kernel_launch(void* const* d_in, const int* in_sizes, int n_in,
                              void* d_out, int out_size, void* d_ws, size_t ws_size,
                              hipStream_t stream) {
  // setup_inputs order: x, Wk, Wq, Wv  (all fp32)
  const float* x  = (const float*)d_in[0];
  const float* Wk = (const float*)d_in[1];
  const float* Wq = (const float*)d_in[2];
  const float* Wv = (const float*)d_in[3];
  float* out = (float*)d_out;

  unsigned short* MtH = (unsigned short*)d_ws;          // [64][64] bf16
  unsigned short* MtL = MtH + 64 * 64;

  mk_m<<<dim3(16), dim3(256), 0, stream>>>(Wq, Wk, MtH, MtL);

  const int batch = in_sizes[0] / (CTX * ND);           // 16384
  head_fused<<<dim3(batch / 4), dim3(256), 0, stream>>>(x, Wv, MtH, MtL, out);
}